// Round 1
// baseline (2021.029 us; speedup 1.0000x reference)
//
#include <hip/hip_runtime.h>
#include <math.h>

// GatedPrototypeDistillationLoss on MI355X (gfx950), fp32 vector-FMA version.
//
// B=32768, D=512, K=2048.  out[0] = L_proto, out[1..B] = gate.
// ws layout: [0..2047] inv_p (1/||p_k||) ; [2048..2048+32768) gate*dist per row.
//
// kmain: BM=32 rows/block, K in 16 tiles of 128 protos, D in 16 tiles of 32.
// E tile (32x512 f32, 64KB) LDS-resident, XOR-swizzled (g ^= row&7).
// P tile (128x32 f32, 16KB) LDS, XOR-swizzled (g ^= (proto>>3)&7), reg-prefetched.
// Micro-tile: 2 rows x 8 protos x 4d; acc in 4 independent d-phase planes (float4).
// Online softmax state (m,s,t,idx) per lane over its 8 protos x 16 ktiles,
// final 16-lane shfl_xor butterfly merge; dist = sqrt(2-2*sim_max).

#define TEMPR 0.07f
#define INV_T (1.0f / 0.07f)
#define NB 32768
#define ND 512
#define NK 2048

#define FMA4(d, a, b)                 \
  d.x = fmaf(a.x, b.x, d.x);          \
  d.y = fmaf(a.y, b.y, d.y);          \
  d.z = fmaf(a.z, b.z, d.z);          \
  d.w = fmaf(a.w, b.w, d.w);

// ---------------- kernel 1: prototype inverse norms ----------------
__global__ __launch_bounds__(256) void knorm_proto(const float* __restrict__ P,
                                                   float* __restrict__ invp) {
  const int lane = threadIdx.x & 63;
  const int wv = threadIdx.x >> 6;
  const int row = blockIdx.x * 4 + wv;  // grid = 512 -> rows 0..2047
  const float4* pr = (const float4*)(P + (size_t)row * ND);
  float4 a = pr[lane];
  float4 b = pr[lane + 64];
  float ss = a.x * a.x + a.y * a.y + a.z * a.z + a.w * a.w
           + b.x * b.x + b.y * b.y + b.z * b.z + b.w * b.w;
#pragma unroll
  for (int off = 32; off > 0; off >>= 1) ss += __shfl_xor(ss, off);
  if (lane == 0) invp[row] = 1.0f / fmaxf(sqrtf(ss), 1e-12f);
}

// ---------------- kernel 2: fused sims + online softmax stats ----------------
__global__ __launch_bounds__(256, 2) void kmain(
    const float* __restrict__ E, const float* __restrict__ BS,
    const float* __restrict__ P, const float* __restrict__ CONF,
    const float* __restrict__ invp, float* __restrict__ gd,
    float* __restrict__ gate_out) {
  __shared__ float eT[32 * 512];   // 64 KB, swizzled
  __shared__ float pT[128 * 32];   // 16 KB, swizzled

  const int t = threadIdx.x;
  const int px = t & 15;        // proto group: protos px*8 .. px*8+7 (of 128)
  const int ry = t >> 4;        // row group: rows 2*ry, 2*ry+1 (of 32)
  const int r0 = 2 * ry, r1 = r0 + 1;
  const int row0 = blockIdx.x * 32;

  float4* eT4 = (float4*)eT;
  float4* pT4 = (float4*)pT;
  const float4* Eg = (const float4*)(E + (size_t)row0 * ND);
  const float4* Pg = (const float4*)P;

  // ---- stage E tile: physical granule slot s=(row,gp) <- source granule gp^(row&7)
#pragma unroll
  for (int i = 0; i < 16; ++i) {
    int s = i * 256 + t;
    int row = s >> 7, gp = s & 127;
    int gs = gp ^ (row & 7);
    eT4[s] = Eg[row * 128 + gs];
  }
  __syncthreads();

  // ---- per-row inverse norms (order-agnostic strip sums over swizzled layout)
  float ss0 = 0.f, ss1 = 0.f;
#pragma unroll
  for (int k = 0; k < 8; ++k) {
    float4 v = eT4[r0 * 128 + px * 8 + k];
    ss0 += v.x * v.x + v.y * v.y + v.z * v.z + v.w * v.w;
    float4 w = eT4[r1 * 128 + px * 8 + k];
    ss1 += w.x * w.x + w.y * w.y + w.z * w.z + w.w * w.w;
  }
#pragma unroll
  for (int off = 1; off < 16; off <<= 1) {
    ss0 += __shfl_xor(ss0, off);
    ss1 += __shfl_xor(ss1, off);
  }
  const float inve0 = 1.0f / fmaxf(sqrtf(ss0), 1e-12f);
  const float inve1 = 1.0f / fmaxf(sqrtf(ss1), 1e-12f);

  const int cA0 = r0 & 7, cA1 = r1 & 7, cB = px & 7;

  // online softmax state per row (logit domain l = sim/T)
  float m[2] = {-INFINITY, -INFINITY};
  float sS[2] = {0.f, 0.f};
  float tS[2] = {0.f, 0.f};
  int idx[2] = {0, 0};

  // prefetch P tile (kt=0, dt=0) into registers (pre-swizzled source)
  float4 stg[4];
#pragma unroll
  for (int i = 0; i < 4; ++i) {
    int s = i * 256 + t;
    int row = s >> 3, gp = s & 7;
    int gs = gp ^ ((row >> 3) & 7);
    stg[i] = Pg[(size_t)row * 128 + gs];
  }

  for (int kt = 0; kt < 16; ++kt) {
    float4 acc[2][8];
#pragma unroll
    for (int r = 0; r < 2; ++r)
#pragma unroll
      for (int p = 0; p < 8; ++p) acc[r][p] = make_float4(0.f, 0.f, 0.f, 0.f);

    for (int dt = 0; dt < 16; ++dt) {
      __syncthreads();  // previous tile's readers done
#pragma unroll
      for (int i = 0; i < 4; ++i) pT4[i * 256 + t] = stg[i];
      // issue next tile's global loads now; latency hides under compute (T14)
      int nk = kt, nd = dt + 1;
      if (nd == 16) { nd = 0; nk = kt + 1; }
      if (nk == 16) { nk = 15; nd = 15; }  // harmless dup on last iter
#pragma unroll
      for (int i = 0; i < 4; ++i) {
        int s = i * 256 + t;
        int row = s >> 3, gp = s & 7;
        int gs = gp ^ ((row >> 3) & 7);
        stg[i] = Pg[(size_t)(nk * 128 + row) * 128 + nd * 8 + gs];
      }
      __syncthreads();  // pT ready

      // compute tile (kt,dt): 8 granule steps x (2 rows x 8 protos) x 4d
#pragma unroll
      for (int gg = 0; gg < 8; ++gg) {
        float4 a0 = eT4[r0 * 128 + dt * 8 + (gg ^ cA0)];
        float4 a1 = eT4[r1 * 128 + dt * 8 + (gg ^ cA1)];
#pragma unroll
        for (int p = 0; p < 8; ++p) {
          float4 b = pT4[(px * 8 + p) * 8 + (gg ^ cB)];
          FMA4(acc[0][p], a0, b);
          FMA4(acc[1][p], a1, b);
        }
      }
    }

    // ---- epilogue for this ktile: fold planes, normalize, online update
    float ipv[8];
#pragma unroll
    for (int p = 0; p < 8; ++p) ipv[p] = invp[kt * 128 + px * 8 + p];
#pragma unroll
    for (int r = 0; r < 2; ++r) {
      float inve = r ? inve1 : inve0;
#pragma unroll
      for (int p = 0; p < 8; ++p) {
        float4 a = acc[r][p];
        float dot = (a.x + a.y) + (a.z + a.w);
        float l = dot * inve * ipv[p] * INV_T;
        float mn = fmaxf(m[r], l);
        float e1 = __expf(m[r] - mn);  // expf(-inf)=0 handles empty state
        float e2 = __expf(l - mn);
        sS[r] = sS[r] * e1 + e2;
        tS[r] = tS[r] * e1 + l * e2;
        if (l > m[r]) idx[r] = kt * 128 + px * 8 + p;  // strict >: first-max wins
        m[r] = mn;
      }
    }
  }

  // ---- butterfly merge across the 16 lanes sharing these rows
#pragma unroll
  for (int r = 0; r < 2; ++r) {
#pragma unroll
    for (int off = 1; off < 16; off <<= 1) {
      float mo = __shfl_xor(m[r], off);
      float so = __shfl_xor(sS[r], off);
      float to = __shfl_xor(tS[r], off);
      int io = __shfl_xor(idx[r], off);
      float mn = fmaxf(m[r], mo);
      float e1 = __expf(m[r] - mn);
      float e2 = __expf(mo - mn);
      sS[r] = sS[r] * e1 + so * e2;
      tS[r] = tS[r] * e1 + to * e2;
      idx[r] = (mo > m[r] || (mo == m[r] && io < idx[r])) ? io : idx[r];
      m[r] = mn;
    }
  }

  if (px == 0) {
    const float max_ent_inv = 1.0f / (logf(2048.0f) + 1e-8f);
#pragma unroll
    for (int r = 0; r < 2; ++r) {
      int row = row0 + r0 + r;
      // entropy = lse - E[l] = m + ln(s) - t/s
      float ent = m[r] + logf(sS[r]) - tS[r] / sS[r];
      float tau = 0.5f - 0.2f * (ent * max_ent_inv);
      float simmax = m[r] * TEMPR;
      float dist = sqrtf(fmaxf(2.0f - 2.0f * simmax, 0.0f));
      float x = (BS[row] - tau) * INV_T;
      float g = CONF[idx[r]] / (1.0f + __expf(-x));
      gate_out[row] = g;
      gd[row] = g * dist;
    }
  }
}

// ---------------- kernel 3: deterministic mean reduction ----------------
__global__ __launch_bounds__(1024) void kreduce(const float* __restrict__ gd,
                                                float* __restrict__ out0) {
  __shared__ float red[1024];
  const int t = threadIdx.x;
  float s = 0.f;
  const float4* g4 = (const float4*)gd;  // 32768 floats = 8192 float4
  for (int i = t; i < 8192; i += 1024) {
    float4 v = g4[i];
    s += (v.x + v.y) + (v.z + v.w);
  }
  red[t] = s;
  __syncthreads();
  for (int off = 512; off > 0; off >>= 1) {
    if (t < off) red[t] += red[t + off];
    __syncthreads();
  }
  if (t == 0) out0[0] = red[0] * (1.0f / 32768.0f);
}

extern "C" void kernel_launch(void* const* d_in, const int* in_sizes, int n_in,
                              void* d_out, int out_size, void* d_ws, size_t ws_size,
                              hipStream_t stream) {
  const float* E = (const float*)d_in[0];     // embeddings [32768,512]
  const float* BS = (const float*)d_in[1];    // best_similarity [32768]
  const float* P = (const float*)d_in[2];     // global_prototypes [2048,512]
  const float* CONF = (const float*)d_in[3];  // prototype_confidence [2048]
  float* out = (float*)d_out;                 // [0]=L_proto, [1..32768]=gate

  float* invp = (float*)d_ws;        // 2048 floats
  float* gd = invp + 2048;           // 32768 floats (gate*dist)

  knorm_proto<<<512, 256, 0, stream>>>(P, invp);
  kmain<<<1024, 256, 0, stream>>>(E, BS, P, CONF, invp, gd, out + 1);
  kreduce<<<1, 1024, 0, stream>>>(gd, out);
}

// Round 2
// 438.761 us; speedup vs baseline: 4.6062x; 4.6062x over previous
//
#include <hip/hip_runtime.h>
#include <math.h>

// GatedPrototypeDistillationLoss, MI355X gfx950 — bf16x3 MFMA version.
// sims = (E/||e||)·(P/||p||)^T via 3-pass bf16 split (hi*hi + hi*lo + lo*hi),
// online softmax stats (fixed-offset, no rescale), near-tie flag + fp32 rescore
// for argmax exactness, dist = sqrt(2-2*simmax).

#define NB 32768
#define ND 512
#define NK 2048
#define TEMPR 0.07f
#define INV_T 14.285714285714286f
#define DX 1.4285714e-4f  // argmax near-tie margin in x-domain (=1e-5 sim / T)

using bf16x8 = __attribute__((ext_vector_type(8))) short;
using f32x16 = __attribute__((ext_vector_type(16))) float;

__device__ inline unsigned short bf_hi(float x) {  // fp32 -> bf16 bits, RNE
  unsigned u = __float_as_uint(x);
  u = u + 0x7FFFu + ((u >> 16) & 1u);
  return (unsigned short)(u >> 16);
}
__device__ inline float bf_tof(unsigned short h) {
  return __uint_as_float(((unsigned)h) << 16);
}
__device__ inline void gload_lds16(const void* g, void* l) {
  __builtin_amdgcn_global_load_lds((const __attribute__((address_space(1))) void*)g,
                                   (__attribute__((address_space(3))) void*)l, 16, 0, 0);
}
#define MF(a, b, c) __builtin_amdgcn_mfma_f32_32x32x16_bf16((a), (b), (c), 0, 0, 0)

// ---------------- kernel 1: P -> normalized bf16 hi/lo; zero flag counter ----
__global__ __launch_bounds__(256) void kprep_p(const float* __restrict__ P,
                                               unsigned short* __restrict__ Phi,
                                               unsigned short* __restrict__ Plo,
                                               int* __restrict__ cnt) {
  if (blockIdx.x == 0 && threadIdx.x == 0) *cnt = 0;
  const int lane = threadIdx.x & 63, w = threadIdx.x >> 6;
  const int row = blockIdx.x * 4 + w;  // grid 512 -> 2048 rows
  const float4* pr = (const float4*)(P + (size_t)row * ND);
  float4 a = pr[lane], b = pr[lane + 64];
  float ss = a.x * a.x + a.y * a.y + a.z * a.z + a.w * a.w
           + b.x * b.x + b.y * b.y + b.z * b.z + b.w * b.w;
#pragma unroll
  for (int off = 32; off > 0; off >>= 1) ss += __shfl_xor(ss, off);
  const float inv = 1.0f / fmaxf(sqrtf(ss), 1e-12f);
  ushort4 h4, l4;
#define PCNV(dst_h, dst_l, f) { float n_ = (f) * inv; unsigned short hb_ = bf_hi(n_); \
  dst_h = hb_; dst_l = bf_hi(n_ - bf_tof(hb_)); }
  PCNV(h4.x, l4.x, a.x) PCNV(h4.y, l4.y, a.y) PCNV(h4.z, l4.z, a.z) PCNV(h4.w, l4.w, a.w)
  *(ushort4*)(Phi + (size_t)row * ND + lane * 4) = h4;
  *(ushort4*)(Plo + (size_t)row * ND + lane * 4) = l4;
  PCNV(h4.x, l4.x, b.x) PCNV(h4.y, l4.y, b.y) PCNV(h4.z, l4.z, b.z) PCNV(h4.w, l4.w, b.w)
  *(ushort4*)(Phi + (size_t)row * ND + (lane + 64) * 4) = h4;
  *(ushort4*)(Plo + (size_t)row * ND + (lane + 64) * 4) = l4;
#undef PCNV
}

// ---------------- kernel 2: embedding inverse norms ----------------
__global__ __launch_bounds__(256) void kprep_e(const float* __restrict__ E,
                                               float* __restrict__ inv_e) {
  const int lane = threadIdx.x & 63, w = threadIdx.x >> 6;
  const int row = blockIdx.x * 4 + w;  // grid 8192 -> 32768 rows
  const float4* er = (const float4*)(E + (size_t)row * ND);
  float4 a = er[lane], b = er[lane + 64];
  float ss = a.x * a.x + a.y * a.y + a.z * a.z + a.w * a.w
           + b.x * b.x + b.y * b.y + b.z * b.z + b.w * b.w;
#pragma unroll
  for (int off = 32; off > 0; off >>= 1) ss += __shfl_xor(ss, off);
  if (lane == 0) inv_e[row] = 1.0f / fmaxf(sqrtf(ss), 1e-12f);
}

// ---------------- kernel 3: MFMA GEMM + online softmax + gating ----------------
__global__ __launch_bounds__(256, 2) void kmain(
    const float* __restrict__ E, const float* __restrict__ BS,
    const unsigned short* __restrict__ Phi, const unsigned short* __restrict__ Plo,
    const float* __restrict__ CONF, const float* __restrict__ inv_e,
    float* __restrict__ tau_ws, float* __restrict__ gd, float* __restrict__ gate_out,
    int* __restrict__ cnt, int* __restrict__ flags) {
  // LDS: A(64x32) hi/lo + B(256x32) hi/lo, double-buffered, granule-swizzled.
  __shared__ unsigned short Ahi[2][2048], Alo[2][2048];
  __shared__ unsigned short Bhi[2][8192], Blo[2][8192];

  const int t = threadIdx.x;
  const int lane = t & 63;
  const int w = t >> 6, wr = w >> 1, wc = w & 1;
  const int c = lane & 31, h = lane >> 5;
  const int swz = (blockIdx.x & 7) * 64 + (blockIdx.x >> 3);  // XCD swizzle (512=8*64)
  const int row0 = swz * 64;

  // A staging assignment: thread t -> (row t>>2, granule t&3), swizzled source
  const int arow_s = t >> 2, agp = t & 3;
  const int agsrc = agp ^ ((arow_s >> 1) & 3);
  const float inve = inv_e[row0 + arow_s];
  const float* Asrc = E + (size_t)(row0 + arow_s) * ND + agsrc * 8;

  // B staging per-instruction source offsets (swizzled)
  int boff[4];
#pragma unroll
  for (int i = 0; i < 4; ++i) {
    int slot = w * 256 + i * 64 + lane;
    int rb = slot >> 2, gpb = slot & 3;
    int gsb = gpb ^ ((rb >> 1) & 3);
    boff[i] = rb * ND + gsb * 8;
  }

  // fragment-read constants
  const int arow4 = (wr * 32 + c) * 4;
  const int axor = ((wr * 32 + c) >> 1) & 3;
  const int bxor = (c >> 1) & 3;
  const int brow4 = (wc * 128 + c) * 4;

  f32x16 acc0, acc1, acc2, acc3;
#pragma unroll
  for (int i = 0; i < 16; ++i) { acc0[i] = 0.f; acc1[i] = 0.f; acc2[i] = 0.f; acc3[i] = 0.f; }
  float sS[16], uS[16], mx[16];
  int ix[16];
  unsigned fl = 0;
#pragma unroll
  for (int r = 0; r < 16; ++r) { sS[r] = 0.f; uS[r] = 0.f; mx[r] = -3.0e38f; ix[r] = 0; }

#define STAGE_B(tkt, tdt, nx) { \
  const int ko_ = (tkt) * 256 * ND + (tdt) * 32; \
  _Pragma("unroll") \
  for (int i = 0; i < 4; ++i) { \
    gload_lds16(Phi + ko_ + boff[i], &Bhi[nx][(w * 256 + i * 64) * 8]); \
    gload_lds16(Plo + ko_ + boff[i], &Blo[nx][(w * 256 + i * 64) * 8]); \
  } }

#define LOAD_A(tdt) { const float4* ap_ = (const float4*)(Asrc + (tdt) * 32); \
  a0 = ap_[0]; a1 = ap_[1]; }

#define ACNV(j, f) { float n_ = (f) * inve; unsigned short hb_ = bf_hi(n_); \
  hv[j] = (short)hb_; lv[j] = (short)bf_hi(n_ - bf_tof(hb_)); }
#define WRITE_A(nx) { bf16x8 hv, lv; \
  ACNV(0, a0.x) ACNV(1, a0.y) ACNV(2, a0.z) ACNV(3, a0.w) \
  ACNV(4, a1.x) ACNV(5, a1.y) ACNV(6, a1.z) ACNV(7, a1.w) \
  *(bf16x8*)&Ahi[nx][t * 8] = hv; *(bf16x8*)&Alo[nx][t * 8] = lv; }

#define KSTEP(ks) { \
  const int ag_ = 2 * (ks) + h; \
  const int ao_ = (arow4 + (ag_ ^ axor)) * 8; \
  const bf16x8 ehi = *(const bf16x8*)&Ahi[cur][ao_]; \
  const bf16x8 elo = *(const bf16x8*)&Alo[cur][ao_]; \
  const int bo_ = (brow4 + (ag_ ^ bxor)) * 8; \
  const bf16x8 bh0 = *(const bf16x8*)&Bhi[cur][bo_]; \
  const bf16x8 bh1 = *(const bf16x8*)&Bhi[cur][bo_ + 1024]; \
  const bf16x8 bh2 = *(const bf16x8*)&Bhi[cur][bo_ + 2048]; \
  const bf16x8 bh3 = *(const bf16x8*)&Bhi[cur][bo_ + 3072]; \
  const bf16x8 bl0 = *(const bf16x8*)&Blo[cur][bo_]; \
  const bf16x8 bl1 = *(const bf16x8*)&Blo[cur][bo_ + 1024]; \
  const bf16x8 bl2 = *(const bf16x8*)&Blo[cur][bo_ + 2048]; \
  const bf16x8 bl3 = *(const bf16x8*)&Blo[cur][bo_ + 3072]; \
  acc0 = MF(ehi, bh0, acc0); acc1 = MF(ehi, bh1, acc1); \
  acc2 = MF(ehi, bh2, acc2); acc3 = MF(ehi, bh3, acc3); \
  acc0 = MF(ehi, bl0, acc0); acc1 = MF(ehi, bl1, acc1); \
  acc2 = MF(ehi, bl2, acc2); acc3 = MF(ehi, bl3, acc3); \
  acc0 = MF(elo, bh0, acc0); acc1 = MF(elo, bh1, acc1); \
  acc2 = MF(elo, bh2, acc2); acc3 = MF(elo, bh3, acc3); }

// online update: x-domain logit, fixed offset; near-tie flag per slot bit
#define UPDV(r, vv, pp) { \
  float x_ = ((vv)-1.0f) * INV_T; \
  float e_ = __expf(x_); \
  sS[r] += e_; uS[r] = fmaf(x_, e_, uS[r]); \
  float d_ = x_ - mx[r]; \
  bool up_ = d_ > 0.0f; \
  bool nr_ = fabsf(d_) < DX; \
  mx[r] = up_ ? x_ : mx[r]; \
  ix[r] = up_ ? (pp) : ix[r]; \
  unsigned b_ = 1u << (r); \
  fl = (up_ ? (fl & ~b_) : fl) | (nr_ ? b_ : 0u); }

  float4 a0, a1;
  // prologue: stage step 0 into buffer 0
  STAGE_B(0, 0, 0);
  LOAD_A(0);
  WRITE_A(0);
  __syncthreads();

  for (int step = 0; step < 128; ++step) {
    const int cur = step & 1, nxt = cur ^ 1;
    const int ns = (step < 127) ? step + 1 : 127;  // last-iter dup is harmless
    STAGE_B(ns >> 4, ns & 15, nxt);
    LOAD_A(ns & 15);
    KSTEP(0);
    KSTEP(1);
    WRITE_A(nxt);  // implicit vmcnt wait on a0/a1
    if ((step & 15) == 15) {
      const int pidb = (step >> 4) * 256 + wc * 128 + c;
#pragma unroll
      for (int r = 0; r < 16; ++r) {
        UPDV(r, acc0[r], pidb)
        UPDV(r, acc1[r], pidb + 32)
        UPDV(r, acc2[r], pidb + 64)
        UPDV(r, acc3[r], pidb + 96)
        acc0[r] = 0.f; acc1[r] = 0.f; acc2[r] = 0.f; acc3[r] = 0.f;
      }
    }
    __syncthreads();  // drains global_load_lds + makes ds_writes visible
  }

  // ---- butterfly merge across the 32 lanes (proto partitions) ----
#pragma unroll
  for (int off = 1; off < 32; off <<= 1) {
    unsigned flo = __shfl_xor(fl, off);
    unsigned nfl = 0u;
#pragma unroll
    for (int r = 0; r < 16; ++r) {
      float mo = __shfl_xor(mx[r], off);
      float so = __shfl_xor(sS[r], off);
      float uo = __shfl_xor(uS[r], off);
      int io = __shfl_xor(ix[r], off);
      sS[r] += so; uS[r] += uo;
      float d = mo - mx[r];
      bool up = d > 0.0f;
      bool nr = fabsf(d) < DX;
      bool f0 = (fl >> r) & 1u, f1 = (flo >> r) & 1u;
      bool fw = (up ? f1 : f0) || nr;
      mx[r] = up ? mo : mx[r];
      ix[r] = up ? io : ix[r];
      nfl |= fw ? (1u << r) : 0u;
    }
    fl = nfl;
  }

  // ---- cross-wave (wc) merge via LDS (alias onto Ahi[0], all compute done) ----
  float* mg = (float*)&Ahi[0][0];  // [wr][wc][32 rows][6]
  if (c == 0) {
#pragma unroll
    for (int r = 0; r < 16; ++r) {
      int rowl = (r & 3) + 8 * (r >> 2) + 4 * h;
      int base = ((wr * 2 + wc) * 32 + rowl) * 6;
      mg[base + 0] = mx[r];
      mg[base + 1] = sS[r];
      mg[base + 2] = uS[r];
      mg[base + 3] = __int_as_float(ix[r]);
      mg[base + 4] = ((fl >> r) & 1u) ? 1.0f : 0.0f;
    }
  }
  __syncthreads();

  if ((w & 1) == 0 && lane < 32) {
    const int rowl = lane;
    const int b0 = ((wr * 2 + 0) * 32 + rowl) * 6;
    const int b1 = ((wr * 2 + 1) * 32 + rowl) * 6;
    float m0 = mg[b0], s0 = mg[b0 + 1], u0 = mg[b0 + 2];
    int i0 = __float_as_int(mg[b0 + 3]);
    bool f0 = mg[b0 + 4] != 0.0f;
    float m1 = mg[b1], s1 = mg[b1 + 1], u1 = mg[b1 + 2];
    int i1 = __float_as_int(mg[b1 + 3]);
    bool f1 = mg[b1 + 4] != 0.0f;
    float d = m1 - m0;
    bool up = d > 0.0f;
    float m = up ? m1 : m0;
    int idx = up ? i1 : i0;
    bool flg = (up ? f1 : f0) || (fabsf(d) < DX);
    float s = s0 + s1, u = u0 + u1;

    float ent = logf(s) - u / s;  // = lse - E[logit]
    float tau = 0.5f - 0.2f * (ent * (1.0f / (7.6246190071f + 1e-8f)));
    float simmax = fmaf(m, TEMPR, 1.0f);  // m is (sim-1)/T
    float dist = sqrtf(fmaxf(2.0f - 2.0f * simmax, 0.0f));
    int grow = row0 + wr * 32 + rowl;
    float g = CONF[idx] / (1.0f + __expf(-(BS[grow] - tau) * INV_T));
    gate_out[grow] = g;
    gd[grow] = g * dist;
    tau_ws[grow] = tau;
    if (flg) {
      int p = atomicAdd(cnt, 1);
      flags[p] = grow;
    }
  }
}

// ---------------- kernel 4: fp32 rescore of near-tie rows ----------------
__global__ __launch_bounds__(256) void krescore(
    const float* __restrict__ E, const float* __restrict__ P,
    const float* __restrict__ BS, const float* __restrict__ CONF,
    const float* __restrict__ tau_ws, const int* __restrict__ cnt,
    const int* __restrict__ flags, float* __restrict__ gd,
    float* __restrict__ gate_out) {
  __shared__ float en[512];
  __shared__ float red[256];
  __shared__ int redi[256];
  __shared__ float sinv;
  const int n = *cnt;
  const int t = threadIdx.x;
  for (int j = blockIdx.x; j < n; j += gridDim.x) {
    const int row = flags[j];
    float2 v = ((const float2*)(E + (size_t)row * ND))[t];
    red[t] = v.x * v.x + v.y * v.y;
    __syncthreads();
    for (int o = 128; o > 0; o >>= 1) {
      if (t < o) red[t] += red[t + o];
      __syncthreads();
    }
    if (t == 0) sinv = 1.0f / fmaxf(sqrtf(red[0]), 1e-12f);
    __syncthreads();
    en[2 * t] = v.x * sinv;
    en[2 * t + 1] = v.y * sinv;
    __syncthreads();
    float best = -3.0e38f;
    int bidx = 0;
    for (int k = 0; k < 8; ++k) {
      const int p = k * 256 + t;
      const float4* pr = (const float4*)(P + (size_t)p * ND);
      float dot = 0.f, pp = 0.f;
      for (int i = 0; i < 128; ++i) {
        float4 a = pr[i];
        float4 e4 = ((const float4*)en)[i];
        dot = fmaf(a.x, e4.x, dot); dot = fmaf(a.y, e4.y, dot);
        dot = fmaf(a.z, e4.z, dot); dot = fmaf(a.w, e4.w, dot);
        pp = fmaf(a.x, a.x, pp); pp = fmaf(a.y, a.y, pp);
        pp = fmaf(a.z, a.z, pp); pp = fmaf(a.w, a.w, pp);
      }
      float sim = dot / fmaxf(sqrtf(pp), 1e-12f);
      if (sim > best) { best = sim; bidx = p; }  // ascending p: first-max kept
    }
    red[t] = best;
    redi[t] = bidx;
    __syncthreads();
    if (t == 0) {
      float bb = red[0];
      int bi = redi[0];
      for (int i = 1; i < 256; ++i) {
        float vv = red[i];
        int ii = redi[i];
        if (vv > bb || (vv == bb && ii < bi)) { bb = vv; bi = ii; }
      }
      float tau = tau_ws[row];
      float dist = sqrtf(fmaxf(2.0f - 2.0f * bb, 0.0f));
      float g = CONF[bi] / (1.0f + __expf(-(BS[row] - tau) * INV_T));
      gate_out[row] = g;
      gd[row] = g * dist;
    }
    __syncthreads();
  }
}

// ---------------- kernel 5: deterministic mean ----------------
__global__ __launch_bounds__(1024) void kreduce(const float* __restrict__ gd,
                                                float* __restrict__ out0) {
  __shared__ float red[1024];
  const int t = threadIdx.x;
  float s = 0.f;
  const float4* g4 = (const float4*)gd;
  for (int i = t; i < 8192; i += 1024) {
    float4 v = g4[i];
    s += (v.x + v.y) + (v.z + v.w);
  }
  red[t] = s;
  __syncthreads();
  for (int off = 512; off > 0; off >>= 1) {
    if (t < off) red[t] += red[t + off];
    __syncthreads();
  }
  if (t == 0) out0[0] = red[0] * (1.0f / 32768.0f);
}

extern "C" void kernel_launch(void* const* d_in, const int* in_sizes, int n_in,
                              void* d_out, int out_size, void* d_ws, size_t ws_size,
                              hipStream_t stream) {
  const float* E = (const float*)d_in[0];
  const float* BS = (const float*)d_in[1];
  const float* P = (const float*)d_in[2];
  const float* CONF = (const float*)d_in[3];
  float* out = (float*)d_out;  // [0]=L_proto, [1..32768]=gate

  char* wsb = (char*)d_ws;
  unsigned short* Phi = (unsigned short*)wsb;                       // 2 MB
  unsigned short* Plo = (unsigned short*)(wsb + (2u << 20));        // 2 MB
  float* inv_e = (float*)(wsb + (4u << 20));                        // 128 KB
  float* tau_ws = (float*)(wsb + (4u << 20) + 131072);              // 128 KB
  float* gd = (float*)(wsb + (4u << 20) + 2 * 131072);              // 128 KB
  int* flags = (int*)(wsb + (4u << 20) + 3 * 131072);               // 128 KB
  int* cnt = (int*)(wsb + (4u << 20) + 4 * 131072);                 // 4 B

  kprep_p<<<512, 256, 0, stream>>>(P, Phi, Plo, cnt);
  kprep_e<<<8192, 256, 0, stream>>>(E, inv_e);
  kmain<<<512, 256, 0, stream>>>(E, BS, Phi, Plo, CONF, inv_e, tau_ws, gd,
                                 out + 1, cnt, flags);
  krescore<<<64, 256, 0, stream>>>(E, P, BS, CONF, tau_ws, cnt, flags, gd, out + 1);
  kreduce<<<1, 1024, 0, stream>>>(gd, out);
}